// Round 1
// baseline (638.510 us; speedup 1.0000x reference)
//
#include <hip/hip_runtime.h>
#include <hip/hip_bf16.h>
#include <cstdint>

// ---------------- config ----------------
#define TSIZE (1u << 22)
#define TMASK (TSIZE - 1u)
#define P1 2654435761u
#define P2 805459861u

typedef _Float16 f16x8 __attribute__((ext_vector_type(8)));
typedef float    f32x4 __attribute__((ext_vector_type(4)));

// packed-weight layout offsets (in halfs) inside d_ws
#define W0_OFF 0        // [256][64]  (K padded 44->64)   16384
#define W1_OFF 16384    // [256][256]                     65536
#define W2_OFF 81920
#define W3_OFF 147456
#define W4_OFF 212992   // [16][256]  (rows padded 3->16)  4096
#define PACK_TOTAL 217088

// LDS layout (bytes)
#define FEAT_OFF 0       // [128 rows][128 B]  (64 fp16 cols, 44 real)
#define ACTA_OFF 16384   // [128 rows][512 B]  (256 fp16 cols)
#define ACTB_OFF 81920
#define SMEM_BYTES 147456

// ------------- weight pre-pack: fp32 -> fp16 in B-fragment order -------------
// dest element index within a layer pack: ((cf*KSTEPS + ks)*64 + lane)*8 + j
// holds W[cf*16 + (lane&15)][ks*32 + (lane>>4)*8 + j]  (0 if out of real range)
__global__ __launch_bounds__(256) void convert_weights(
    const float* __restrict__ W0, const float* __restrict__ W1,
    const float* __restrict__ W2, const float* __restrict__ W3,
    const float* __restrict__ W4, _Float16* __restrict__ ws)
{
    int gid = blockIdx.x * 256 + threadIdx.x;
    if (gid >= PACK_TOTAL) return;
    const int   offs[6] = {W0_OFF, W1_OFF, W2_OFF, W3_OFF, W4_OFF, PACK_TOTAL};
    const int   outR[5] = {256, 256, 256, 256, 3};
    const int   kR[5]   = {44, 256, 256, 256, 256};
    const int   kst[5]  = {2, 8, 8, 8, 8};
    const float* Ws[5]  = {W0, W1, W2, W3, W4};
    int l = 0;
    while (gid >= offs[l + 1]) ++l;
    int local = gid - offs[l];
    int j    = local & 7;
    int lane = (local >> 3) & 63;
    int t    = local >> 9;             // cf*ksteps + ks
    int ks   = t & (kst[l] - 1);       // ksteps is a power of two
    int cf   = t / kst[l];
    int o = cf * 16 + (lane & 15);
    int k = ks * 32 + ((lane >> 4) << 3) + j;
    float v = 0.f;
    if (o < outR[l] && k < kR[l]) v = Ws[l][o * kR[l] + k];
    ws[gid] = (_Float16)v;
}

// ------------- fused encode + MLP -------------
// A-frag (m x k): lane holds act[row = l&15][k = ks*32 + (l>>4)*8 + j]
// B-frag (k x n): lane holds W[col = l&15][same k]  (pre-packed)
// D-frag:         lane holds D[row = (l>>4)*4 + r][col = l&15]
template <int KSTEPS, int SSTRIDE>
__device__ inline void mlp_layer(const char* __restrict__ src, char* __restrict__ dst,
                                 const f16x8* __restrict__ wp, const float* __restrict__ bias,
                                 int wave, int lane, bool relu)
{
    f32x4 acc[8][2];
    #pragma unroll
    for (int i = 0; i < 8; ++i) {
        acc[i][0] = f32x4{0.f, 0.f, 0.f, 0.f};
        acc[i][1] = f32x4{0.f, 0.f, 0.f, 0.f};
    }
    const int cf0 = wave * 2;
    #pragma unroll 2
    for (int ks = 0; ks < KSTEPS; ++ks) {
        f16x8 b0 = wp[(cf0 * KSTEPS + ks) * 64 + lane];
        f16x8 b1 = wp[((cf0 + 1) * KSTEPS + ks) * 64 + lane];
        int kb = ks * 64 + ((lane >> 4) << 4);
        #pragma unroll
        for (int rf = 0; rf < 8; ++rf) {
            int row = rf * 16 + (lane & 15);
            f16x8 a = *(const f16x8*)(src + row * SSTRIDE + (kb ^ ((row & 7) << 4)));
            acc[rf][0] = __builtin_amdgcn_mfma_f32_16x16x32_f16(a, b0, acc[rf][0], 0, 0, 0);
            acc[rf][1] = __builtin_amdgcn_mfma_f32_16x16x32_f16(a, b1, acc[rf][1], 0, 0, 0);
        }
    }
    #pragma unroll
    for (int rf = 0; rf < 8; ++rf) {
        #pragma unroll
        for (int c = 0; c < 2; ++c) {
            int col = wave * 32 + c * 16 + (lane & 15);
            float bv = bias[col];
            #pragma unroll
            for (int r = 0; r < 4; ++r) {
                int row = rf * 16 + ((lane >> 4) << 2) + r;
                float v = acc[rf][c][r] + bv;
                if (relu) v = fmaxf(v, 0.f);
                *(_Float16*)(dst + row * 512 + ((col * 2) ^ ((row & 7) << 4))) = (_Float16)v;
            }
        }
    }
}

__global__ __launch_bounds__(512, 2) void nrfield_fused(
    const float* __restrict__ X,  const float* __restrict__ WI,
    const float* __restrict__ NRM, const float* __restrict__ FD,
    const float* __restrict__ TBL,
    const float* __restrict__ B0, const float* __restrict__ B1,
    const float* __restrict__ B2, const float* __restrict__ B3,
    const float* __restrict__ B4,
    const _Float16* __restrict__ WS,
    float* __restrict__ OUT, int N)
{
    extern __shared__ char smem[];
    char* feat = smem + FEAT_OFF;
    char* actA = smem + ACTA_OFF;
    char* actB = smem + ACTB_OFF;

    const int tid  = threadIdx.x;
    const int wave = tid >> 6, lane = tid & 63;
    const int p = tid >> 2, q = tid & 3;           // 4 threads per point
    const int gp = blockIdx.x * 128 + p;

    auto fw = [&](int row, int col, float v) {
        *(_Float16*)(feat + row * 128 + ((col * 2) ^ ((row & 7) << 4))) = (_Float16)v;
    };

    // ---- encode phase: hash-grid trilinear, 2 levels per thread ----
    if (gp < N) {
        float x0 = X[gp * 3 + 0], x1 = X[gp * 3 + 1], x2 = X[gp * 3 + 2];
        #pragma unroll
        for (int s = 0; s < 2; ++s) {
            int lvl = q * 2 + s;
            float res = (float)(16 << lvl);
            float px = x0 * res, py = x1 * res, pz = x2 * res;
            float fx = floorf(px), fy = floorf(py), fz = floorf(pz);
            float wx = px - fx, wy = py - fy, wz = pz - fz;
            float ux = 1.f - wx, uy = 1.f - wy, uz = 1.f - wz;
            uint32_t hx0 = (uint32_t)(int)fx, hx1 = hx0 + 1u;
            uint32_t hy0 = (uint32_t)(int)fy * P1, hy1 = hy0 + P1;
            uint32_t hz0 = (uint32_t)(int)fz * P2, hz1 = hz0 + P2;
            const float4* tl = (const float4*)TBL + ((size_t)lvl << 22);
            float a0 = 0.f, a1 = 0.f, a2 = 0.f, a3 = 0.f;
            #pragma unroll
            for (int c = 0; c < 8; ++c) {
                uint32_t h = ((c & 4) ? hx1 : hx0) ^ ((c & 2) ? hy1 : hy0) ^ ((c & 1) ? hz1 : hz0);
                float4 g = tl[h & TMASK];
                float cw = ((c & 4) ? wx : ux) * ((c & 2) ? wy : uy);
                cw *= ((c & 1) ? wz : uz);
                a0 += g.x * cw; a1 += g.y * cw; a2 += g.z * cw; a3 += g.w * cw;
            }
            int cb = 12 + lvl * 4;
            fw(p, cb + 0, a0); fw(p, cb + 1, a1); fw(p, cb + 2, a2); fw(p, cb + 3, a3);
        }
        if (q == 0) {
            fw(p, 0, x0); fw(p, 1, x1); fw(p, 2, x2);
            fw(p, 3, WI[gp * 3]);  fw(p, 4, WI[gp * 3 + 1]);  fw(p, 5, WI[gp * 3 + 2]);
            fw(p, 6, NRM[gp * 3]); fw(p, 7, NRM[gp * 3 + 1]); fw(p, 8, NRM[gp * 3 + 2]);
            fw(p, 9, FD[gp * 3]);  fw(p, 10, FD[gp * 3 + 1]); fw(p, 11, FD[gp * 3 + 2]);
            for (int cc = 44; cc < 64; ++cc) fw(p, cc, 0.f);  // zero pad (NaN x 0 = NaN!)
        }
    }
    __syncthreads();

    // ---- MLP: 44(->64) -> 256 -> 256 -> 256 -> 256 -> 3 ----
    mlp_layer<2, 128>(feat, actA, (const f16x8*)(WS + W0_OFF), B0, wave, lane, true);
    __syncthreads();
    mlp_layer<8, 512>(actA, actB, (const f16x8*)(WS + W1_OFF), B1, wave, lane, true);
    __syncthreads();
    mlp_layer<8, 512>(actB, actA, (const f16x8*)(WS + W2_OFF), B2, wave, lane, true);
    __syncthreads();
    mlp_layer<8, 512>(actA, actB, (const f16x8*)(WS + W3_OFF), B3, wave, lane, true);
    __syncthreads();

    // final layer: each wave owns a 16-row stripe, 1 col-frag (cols 0..15, 3 real)
    f32x4 acc = f32x4{0.f, 0.f, 0.f, 0.f};
    const f16x8* wp4 = (const f16x8*)(WS + W4_OFF);
    {
        int row = wave * 16 + (lane & 15);
        #pragma unroll
        for (int ks = 0; ks < 8; ++ks) {
            f16x8 b = wp4[ks * 64 + lane];
            int kb = ks * 64 + ((lane >> 4) << 4);
            f16x8 a = *(const f16x8*)(actB + row * 512 + (kb ^ ((row & 7) << 4)));
            acc = __builtin_amdgcn_mfma_f32_16x16x32_f16(a, b, acc, 0, 0, 0);
        }
    }
    int col = lane & 15;
    if (col < 3) {
        float bv = B4[col];
        #pragma unroll
        for (int r = 0; r < 4; ++r) {
            int row = wave * 16 + ((lane >> 4) << 2) + r;
            int g = blockIdx.x * 128 + row;
            if (g < N) OUT[g * 3 + col] = fabsf(acc[r] + bv);
        }
    }
}

extern "C" void kernel_launch(void* const* d_in, const int* in_sizes, int n_in,
                              void* d_out, int out_size, void* d_ws, size_t ws_size,
                              hipStream_t stream)
{
    const float* X   = (const float*)d_in[0];
    const float* WI  = (const float*)d_in[1];
    const float* NRM = (const float*)d_in[2];
    const float* FD  = (const float*)d_in[3];
    const float* TBL = (const float*)d_in[4];
    const float* W0  = (const float*)d_in[5];
    const float* B0  = (const float*)d_in[6];
    const float* W1  = (const float*)d_in[7];
    const float* B1  = (const float*)d_in[8];
    const float* W2  = (const float*)d_in[9];
    const float* B2  = (const float*)d_in[10];
    const float* W3  = (const float*)d_in[11];
    const float* B3  = (const float*)d_in[12];
    const float* W4  = (const float*)d_in[13];
    const float* B4  = (const float*)d_in[14];
    float* OUT = (float*)d_out;

    int N = in_sizes[0] / 3;
    _Float16* ws = (_Float16*)d_ws;

    convert_weights<<<(PACK_TOTAL + 255) / 256, 256, 0, stream>>>(W0, W1, W2, W3, W4, ws);

    hipFuncSetAttribute((const void*)nrfield_fused,
                        hipFuncAttributeMaxDynamicSharedMemorySize, SMEM_BYTES);
    int grid = (N + 127) / 128;
    nrfield_fused<<<grid, 512, SMEM_BYTES, stream>>>(X, WI, NRM, FD, TBL,
                                                     B0, B1, B2, B3, B4, ws, OUT, N);
}

// Round 2
// 618.219 us; speedup vs baseline: 1.0328x; 1.0328x over previous
//
#include <hip/hip_runtime.h>
#include <hip/hip_bf16.h>
#include <cstdint>

// ---------------- config ----------------
#define TSIZE (1u << 22)
#define TMASK (TSIZE - 1u)
#define P1 2654435761u
#define P2 805459861u

typedef _Float16 f16x8 __attribute__((ext_vector_type(8)));
typedef _Float16 f16x4 __attribute__((ext_vector_type(4)));
typedef float    f32x4 __attribute__((ext_vector_type(4)));

// packed-weight layout offsets (in halfs) inside d_ws
#define W0_OFF 0        // [256][64]  (K padded 44->64)   16384
#define W1_OFF 16384    // [256][256]                     65536
#define W2_OFF 81920
#define W3_OFF 147456
#define W4_OFF 212992   // [16][256]  (rows padded 3->16)  4096
#define PACK_TOTAL 217088

// bf16 fine-table (levels 4..7) region in d_ws
#define TB16_BYTE_OFF 524288ull                      // 512 KB (after weights)
#define TB16_BYTES    (4ull * TSIZE * 4ull * 2ull)   // 4 levels * 4M * 4 feat * 2B = 128 MB
#define WS_NEED       (TB16_BYTE_OFF + TB16_BYTES)

// LDS layout (bytes) — 64 points per block
#define FEAT_OFF 0       // [64 rows][128 B]  (64 fp16 cols, 44 real)
#define ACTA_OFF 8192    // [64 rows][512 B]  (256 fp16 cols)
#define ACTB_OFF 40960
#define SMEM_BYTES 73728 // 72 KB -> 2 blocks/CU

// ------------- weight pre-pack: fp32 -> fp16 in B-fragment order -------------
// dest element index within a layer pack: ((cf*KSTEPS + ks)*64 + lane)*8 + j
// holds W[cf*16 + (lane&15)][ks*32 + (lane>>4)*8 + j]  (0 if out of real range)
__global__ __launch_bounds__(256) void convert_weights(
    const float* __restrict__ W0, const float* __restrict__ W1,
    const float* __restrict__ W2, const float* __restrict__ W3,
    const float* __restrict__ W4, _Float16* __restrict__ ws)
{
    int gid = blockIdx.x * 256 + threadIdx.x;
    if (gid >= PACK_TOTAL) return;
    const int   offs[6] = {W0_OFF, W1_OFF, W2_OFF, W3_OFF, W4_OFF, PACK_TOTAL};
    const int   outR[5] = {256, 256, 256, 256, 3};
    const int   kR[5]   = {44, 256, 256, 256, 256};
    const int   kst[5]  = {2, 8, 8, 8, 8};
    const float* Ws[5]  = {W0, W1, W2, W3, W4};
    int l = 0;
    while (gid >= offs[l + 1]) ++l;
    int local = gid - offs[l];
    int j    = local & 7;
    int lane = (local >> 3) & 63;
    int t    = local >> 9;             // cf*ksteps + ks
    int ks   = t & (kst[l] - 1);       // ksteps is a power of two
    int cf   = t / kst[l];
    int o = cf * 16 + (lane & 15);
    int k = ks * 32 + ((lane >> 4) << 3) + j;
    float v = 0.f;
    if (o < outR[l] && k < kR[l]) v = Ws[l][o * kR[l] + k];
    ws[gid] = (_Float16)v;
}

// ------------- fine-table fp32 -> bf16 (levels 4..7), 2 entries/thread -------------
__device__ inline uint32_t pack_bf16(float lo, float hi) {
    uint32_t ul = __float_as_uint(lo), uh = __float_as_uint(hi);
    ul = (ul + 0x7fffu + ((ul >> 16) & 1u)) >> 16;
    uh = (uh + 0x7fffu + ((uh >> 16) & 1u)) >> 16;
    return ul | (uh << 16);
}

__global__ __launch_bounds__(256) void convert_table(
    const float* __restrict__ TBL, uint32_t* __restrict__ tb16)
{
    size_t t = (size_t)blockIdx.x * 256 + threadIdx.x;   // 0 .. 8M-1
    const float4* src = (const float4*)TBL + (4ull << 22) + t * 2;
    float4 a = src[0], b = src[1];
    uint4 o;
    o.x = pack_bf16(a.x, a.y); o.y = pack_bf16(a.z, a.w);
    o.z = pack_bf16(b.x, b.y); o.w = pack_bf16(b.z, b.w);
    ((uint4*)tb16)[t] = o;
}

// ------------- fused encode + MLP (64 points / 256 threads / 4 waves) -------------
// A-frag (m x k): lane holds act[row = l&15][k = ks*32 + (l>>4)*8 + j]
// B-frag (k x n): lane holds W[col = l&15][same k]  (pre-packed)
// D-frag:         lane holds D[row = (l>>4)*4 + r][col = l&15]
template <int KSTEPS, int SSTRIDE>
__device__ inline void mlp_layer(const char* __restrict__ src, char* __restrict__ dst,
                                 const f16x8* __restrict__ wp, const float* __restrict__ bias,
                                 int wave, int lane, bool relu)
{
    f32x4 acc[4][4];
    #pragma unroll
    for (int i = 0; i < 4; ++i)
        #pragma unroll
        for (int c = 0; c < 4; ++c)
            acc[i][c] = f32x4{0.f, 0.f, 0.f, 0.f};
    const int cf0 = wave * 4;
    #pragma unroll 2
    for (int ks = 0; ks < KSTEPS; ++ks) {
        f16x8 b[4];
        #pragma unroll
        for (int c = 0; c < 4; ++c)
            b[c] = wp[((cf0 + c) * KSTEPS + ks) * 64 + lane];
        int kb = ks * 64 + ((lane >> 4) << 4);
        #pragma unroll
        for (int rf = 0; rf < 4; ++rf) {
            int row = rf * 16 + (lane & 15);
            f16x8 a = *(const f16x8*)(src + row * SSTRIDE + (kb ^ ((row & 7) << 4)));
            #pragma unroll
            for (int c = 0; c < 4; ++c)
                acc[rf][c] = __builtin_amdgcn_mfma_f32_16x16x32_f16(a, b[c], acc[rf][c], 0, 0, 0);
        }
    }
    #pragma unroll
    for (int rf = 0; rf < 4; ++rf) {
        #pragma unroll
        for (int c = 0; c < 4; ++c) {
            int col = wave * 64 + c * 16 + (lane & 15);
            float bv = bias[col];
            #pragma unroll
            for (int r = 0; r < 4; ++r) {
                int row = rf * 16 + ((lane >> 4) << 2) + r;
                float v = acc[rf][c][r] + bv;
                if (relu) v = fmaxf(v, 0.f);
                *(_Float16*)(dst + row * 512 + ((col * 2) ^ ((row & 7) << 4))) = (_Float16)v;
            }
        }
    }
}

__global__ __launch_bounds__(256, 2) void nrfield_fused(
    const float* __restrict__ X,  const float* __restrict__ WI,
    const float* __restrict__ NRM, const float* __restrict__ FD,
    const float* __restrict__ TBL,
    const float* __restrict__ B0, const float* __restrict__ B1,
    const float* __restrict__ B2, const float* __restrict__ B3,
    const float* __restrict__ B4,
    const _Float16* __restrict__ WS, const ushort* __restrict__ TB16,
    float* __restrict__ OUT, int N, int useBf16)
{
    extern __shared__ char smem[];
    char* feat = smem + FEAT_OFF;
    char* actA = smem + ACTA_OFF;
    char* actB = smem + ACTB_OFF;

    const int tid  = threadIdx.x;
    const int wave = tid >> 6, lane = tid & 63;
    const int p = lane;                  // point within block
    const int gp = blockIdx.x * 64 + p;

    // swizzled 8B feature write (col must be %4==0)
    auto fw4 = [&](int row, int col, f16x4 v) {
        *(f16x4*)(feat + row * 128 + ((col * 2) ^ ((row & 7) << 4))) = v;
    };

    // ---- encode phase: wave w handles levels 2w, 2w+1 for all 64 points ----
    if (gp < N) {
        float x0 = X[gp * 3 + 0], x1 = X[gp * 3 + 1], x2 = X[gp * 3 + 2];
        #pragma unroll
        for (int s = 0; s < 2; ++s) {
            int lvl = wave * 2 + s;
            float res = (float)(16 << lvl);
            float px = x0 * res, py = x1 * res, pz = x2 * res;
            float fx = floorf(px), fy = floorf(py), fz = floorf(pz);
            float wx = px - fx, wy = py - fy, wz = pz - fz;
            float ux = 1.f - wx, uy = 1.f - wy, uz = 1.f - wz;
            uint32_t hx0 = (uint32_t)(int)fx, hx1 = hx0 + 1u;
            uint32_t hy0 = (uint32_t)(int)fy * P1, hy1 = hy0 + P1;
            uint32_t hz0 = (uint32_t)(int)fz * P2, hz1 = hz0 + P2;
            float a0 = 0.f, a1 = 0.f, a2 = 0.f, a3 = 0.f;
            if (useBf16 && lvl >= 4) {               // wave-uniform branch
                const ushort4* tl = (const ushort4*)TB16 + ((size_t)(lvl - 4) << 22);
                #pragma unroll
                for (int c = 0; c < 8; ++c) {
                    uint32_t h = ((c & 4) ? hx1 : hx0) ^ ((c & 2) ? hy1 : hy0) ^ ((c & 1) ? hz1 : hz0);
                    ushort4 g = tl[h & TMASK];
                    float cw = ((c & 4) ? wx : ux) * ((c & 2) ? wy : uy) * ((c & 1) ? wz : uz);
                    a0 += __uint_as_float((uint32_t)g.x << 16) * cw;
                    a1 += __uint_as_float((uint32_t)g.y << 16) * cw;
                    a2 += __uint_as_float((uint32_t)g.z << 16) * cw;
                    a3 += __uint_as_float((uint32_t)g.w << 16) * cw;
                }
            } else {
                const float4* tl = (const float4*)TBL + ((size_t)lvl << 22);
                #pragma unroll
                for (int c = 0; c < 8; ++c) {
                    uint32_t h = ((c & 4) ? hx1 : hx0) ^ ((c & 2) ? hy1 : hy0) ^ ((c & 1) ? hz1 : hz0);
                    float4 g = tl[h & TMASK];
                    float cw = ((c & 4) ? wx : ux) * ((c & 2) ? wy : uy) * ((c & 1) ? wz : uz);
                    a0 += g.x * cw; a1 += g.y * cw; a2 += g.z * cw; a3 += g.w * cw;
                }
            }
            fw4(p, 12 + lvl * 4, f16x4{(_Float16)a0, (_Float16)a1, (_Float16)a2, (_Float16)a3});
        }
        if (wave == 0) {
            fw4(p, 0, f16x4{(_Float16)x0, (_Float16)x1, (_Float16)x2, (_Float16)WI[gp * 3]});
            fw4(p, 4, f16x4{(_Float16)WI[gp * 3 + 1], (_Float16)WI[gp * 3 + 2],
                            (_Float16)NRM[gp * 3], (_Float16)NRM[gp * 3 + 1]});
            fw4(p, 8, f16x4{(_Float16)NRM[gp * 3 + 2], (_Float16)FD[gp * 3],
                            (_Float16)FD[gp * 3 + 1], (_Float16)FD[gp * 3 + 2]});
            f16x4 z{(_Float16)0.f, (_Float16)0.f, (_Float16)0.f, (_Float16)0.f};
            #pragma unroll
            for (int cc = 44; cc < 64; cc += 4) fw4(p, cc, z);   // zero pad (NaN x 0 = NaN!)
        }
    }
    __syncthreads();

    // ---- MLP: 44(->64) -> 256 -> 256 -> 256 -> 256 -> 3 ----
    mlp_layer<2, 128>(feat, actA, (const f16x8*)(WS + W0_OFF), B0, wave, lane, true);
    __syncthreads();
    mlp_layer<8, 512>(actA, actB, (const f16x8*)(WS + W1_OFF), B1, wave, lane, true);
    __syncthreads();
    mlp_layer<8, 512>(actB, actA, (const f16x8*)(WS + W2_OFF), B2, wave, lane, true);
    __syncthreads();
    mlp_layer<8, 512>(actA, actB, (const f16x8*)(WS + W3_OFF), B3, wave, lane, true);
    __syncthreads();

    // final layer: each wave owns a 16-row stripe, 1 col-frag (cols 0..15, 3 real)
    f32x4 acc = f32x4{0.f, 0.f, 0.f, 0.f};
    const f16x8* wp4 = (const f16x8*)(WS + W4_OFF);
    {
        int row = wave * 16 + (lane & 15);
        #pragma unroll
        for (int ks = 0; ks < 8; ++ks) {
            f16x8 b = wp4[ks * 64 + lane];
            int kb = ks * 64 + ((lane >> 4) << 4);
            f16x8 a = *(const f16x8*)(actB + row * 512 + (kb ^ ((row & 7) << 4)));
            acc = __builtin_amdgcn_mfma_f32_16x16x32_f16(a, b, acc, 0, 0, 0);
        }
    }
    int col = lane & 15;
    if (col < 3) {
        float bv = B4[col];
        #pragma unroll
        for (int r = 0; r < 4; ++r) {
            int row = wave * 16 + ((lane >> 4) << 2) + r;
            int g = blockIdx.x * 64 + row;
            if (g < N) OUT[g * 3 + col] = fabsf(acc[r] + bv);
        }
    }
}

extern "C" void kernel_launch(void* const* d_in, const int* in_sizes, int n_in,
                              void* d_out, int out_size, void* d_ws, size_t ws_size,
                              hipStream_t stream)
{
    const float* X   = (const float*)d_in[0];
    const float* WI  = (const float*)d_in[1];
    const float* NRM = (const float*)d_in[2];
    const float* FD  = (const float*)d_in[3];
    const float* TBL = (const float*)d_in[4];
    const float* W0  = (const float*)d_in[5];
    const float* B0  = (const float*)d_in[6];
    const float* W1  = (const float*)d_in[7];
    const float* B1  = (const float*)d_in[8];
    const float* W2  = (const float*)d_in[9];
    const float* B2  = (const float*)d_in[10];
    const float* W3  = (const float*)d_in[11];
    const float* B3  = (const float*)d_in[12];
    const float* W4  = (const float*)d_in[13];
    const float* B4  = (const float*)d_in[14];
    float* OUT = (float*)d_out;

    int N = in_sizes[0] / 3;
    _Float16* ws = (_Float16*)d_ws;
    int useBf16 = (ws_size >= WS_NEED) ? 1 : 0;
    ushort* tb16 = (ushort*)((char*)d_ws + TB16_BYTE_OFF);

    convert_weights<<<(PACK_TOTAL + 255) / 256, 256, 0, stream>>>(W0, W1, W2, W3, W4, ws);
    if (useBf16) {
        // 4 levels * 4M entries, 2 entries/thread
        convert_table<<<32768, 256, 0, stream>>>(TBL, (uint32_t*)tb16);
    }

    hipFuncSetAttribute((const void*)nrfield_fused,
                        hipFuncAttributeMaxDynamicSharedMemorySize, SMEM_BYTES);
    int grid = (N + 63) / 64;
    nrfield_fused<<<grid, 256, SMEM_BYTES, stream>>>(X, WI, NRM, FD, TBL,
                                                     B0, B1, B2, B3, B4, ws, tb16,
                                                     OUT, N, useBf16);
}